// Round 7
// baseline (183.331 us; speedup 1.0000x reference)
//
#include <hip/hip_runtime.h>

#define NN 100000
#define SS 50000
#define KK 32
#define CC 128
#define RPB 160          // rows per proj block; 625 * 160 = 100000
#define LDA 136          // LDS row stride in halfs (272 B)

typedef _Float16 f16x8 __attribute__((ext_vector_type(8)));
typedef _Float16 f16x4 __attribute__((ext_vector_type(4)));
typedef _Float16 f16x2 __attribute__((ext_vector_type(2)));
typedef float f32x4 __attribute__((ext_vector_type(4)));

// Workspace table T: per row i (512 B stride, 256 halfs):
//   T[i*256 +   0 .. 127] = fp16(word_vec[i])   (proj staging loop)
//   T[i*256 + 128 .. 255] = fp16(P[i])          (proj epilogue)

// ---------------------------------------------------------------------------
// Kernel 1 (fused convert+proj), mfma_f32_16x16x32_f16 with A=W, B=wv:
// D[m=ocol][n=wvrow] so each lane's 4 acc regs are 4 CONSECUTIVE out columns
// -> float4/f16x4 epilogue stores (R6 had 16 scalar dword+short stores).
// 160 rows staged once to LDS fp16 (same loop publishes wv-half of T).
// ---------------------------------------------------------------------------
__global__ __launch_bounds__(256) void proj_kernel(
    const float* __restrict__ wv,
    const float* __restrict__ W,
    const float* __restrict__ bias,
    _Float16* __restrict__ T,
    float* __restrict__ out)
{
    __shared__ _Float16 sA[RPB][LDA];

    const int t = threadIdx.x;
    const int base = blockIdx.x * RPB;

    // Stage A (160 x 128 fp32 -> fp16 LDS + T copy). 20 float4 per thread.
    #pragma unroll 4
    for (int i = 0; i < 20; i++) {
        const int idx = i * 256 + t;
        const int row = idx >> 5;
        const int c4 = (idx & 31) * 4;
        const float4 v = *(const float4*)(wv + (size_t)(base + row) * CC + c4);
        f16x4 h;
        h[0] = (_Float16)v.x; h[1] = (_Float16)v.y;
        h[2] = (_Float16)v.z; h[3] = (_Float16)v.w;
        *(f16x4*)&sA[row][c4] = h;
        *(f16x4*)(T + (size_t)(base + row) * 256 + c4) = h;
    }

    const int w = t >> 6;
    const int l = t & 63;
    const int q = l >> 4;      // quad 0..3
    const int c = l & 15;

    // A-frags = W rows (register-resident): lane holds A[m=c][k=kc*32+q*8+j],
    // m-tile base = nch*64 + w*16.
    f16x8 af[2][4];
    float4 bv[2];
    #pragma unroll
    for (int nch = 0; nch < 2; nch++) {
        const int ocol_row = nch * 64 + w * 16 + c;
        const float* Wr = W + (size_t)ocol_row * CC;
        bv[nch] = *(const float4*)(bias + nch * 64 + w * 16 + q * 4);
        #pragma unroll
        for (int kc = 0; kc < 4; kc++) {
            const int k0 = kc * 32 + q * 8;
            const float4 w0 = *(const float4*)(Wr + k0);
            const float4 w1 = *(const float4*)(Wr + k0 + 4);
            f16x8 a;
            a[0] = (_Float16)w0.x; a[1] = (_Float16)w0.y;
            a[2] = (_Float16)w0.z; a[3] = (_Float16)w0.w;
            a[4] = (_Float16)w1.x; a[5] = (_Float16)w1.y;
            a[6] = (_Float16)w1.z; a[7] = (_Float16)w1.w;
            af[nch][kc] = a;
        }
    }
    __syncthreads();

    #pragma unroll 2
    for (int sub = 0; sub < RPB / 16; sub++) {
        // B-frags from LDS: lane holds B[k=kc*32+q*8+j][n=c] = wv_h row c.
        f16x8 bf[4];
        #pragma unroll
        for (int kc = 0; kc < 4; kc++)
            bf[kc] = *(const f16x8*)&sA[sub * 16 + c][kc * 32 + q * 8];

        f32x4 acc[2] = {{0.f, 0.f, 0.f, 0.f}, {0.f, 0.f, 0.f, 0.f}};
        #pragma unroll
        for (int kc = 0; kc < 4; kc++) {
            acc[0] = __builtin_amdgcn_mfma_f32_16x16x32_f16(af[0][kc], bf[kc], acc[0], 0, 0, 0);
            acc[1] = __builtin_amdgcn_mfma_f32_16x16x32_f16(af[1][kc], bf[kc], acc[1], 0, 0, 0);
        }

        // D: n(col)=c -> wv row, m(row)=q*4+r -> ocol. 4 consecutive ocols
        // per lane -> vector epilogue stores.
        const int grow = base + sub * 16 + c;
        #pragma unroll
        for (int nch = 0; nch < 2; nch++) {
            const int col0 = nch * 64 + w * 16 + q * 4;
            float4 o;
            o.x = acc[nch][0] + bv[nch].x;
            o.y = acc[nch][1] + bv[nch].y;
            o.z = acc[nch][2] + bv[nch].z;
            o.w = acc[nch][3] + bv[nch].w;
            o.x = fmaxf(o.x, 0.2f * o.x);
            o.y = fmaxf(o.y, 0.2f * o.y);
            o.z = fmaxf(o.z, 0.2f * o.z);
            o.w = fmaxf(o.w, 0.2f * o.w);
            *(float4*)(out + (size_t)grow * CC + col0) = o;
            f16x4 h;
            h[0] = (_Float16)o.x; h[1] = (_Float16)o.y;
            h[2] = (_Float16)o.z; h[3] = (_Float16)o.w;
            *(f16x4*)(T + (size_t)grow * 256 + 128 + col0) = h;
        }
    }
}

// ---------------------------------------------------------------------------
// Kernel 2: one wave per s, lane = r*16+c. Lane-group r owns neighbors
// k = r*8 + ch (contiguous -> int4-vectorized neighs/mask loads; softmax is
// permutation-invariant so the remap is free). Gathers batched + mask-skipped
// via address redirect to the hot src row.
// ---------------------------------------------------------------------------
__global__ __launch_bounds__(256) void attn_kernel(
    const _Float16* __restrict__ T,
    const int* __restrict__ src_idx,
    const int* __restrict__ neighs,
    const int* __restrict__ mask,
    float* __restrict__ out)
{
    const int s = (blockIdx.x * 256 + threadIdx.x) >> 6;
    if (s >= SS) return;
    const int lane = threadIdx.x & 63;
    const int c = lane & 15;
    const int r = lane >> 4;

    // k = r*8 + ch: two int4 loads each for neighbors and masks.
    const int4 n0 = *(const int4*)(neighs + s * KK + r * 8);
    const int4 n1 = *(const int4*)(neighs + s * KK + r * 8 + 4);
    const int4 m0 = *(const int4*)(mask   + s * KK + r * 8);
    const int4 m1 = *(const int4*)(mask   + s * KK + r * 8 + 4);
    const int nbv[8] = {n0.x, n0.y, n0.z, n0.w, n1.x, n1.y, n1.z, n1.w};
    const int mv[8]  = {m0.x, m0.y, m0.z, m0.w, m1.x, m1.y, m1.z, m1.w};

    const int src = src_idx[s];
    const f16x8 qh = *(const f16x8*)(T + (size_t)src * 256 + c * 8);

    // Score gathers: batched, masked rows redirected to src (no new lines).
    f16x8 kh[8];
    #pragma unroll
    for (int ch = 0; ch < 8; ch++) {
        const int row = (mv[ch] == 1) ? nbv[ch] : src;
        kh[ch] = *(const f16x8*)(T + (size_t)row * 256 + c * 8);
    }

    float sc[8];
    #pragma unroll
    for (int ch = 0; ch < 8; ch++) {
        float d = 0.f;
        #pragma unroll
        for (int j = 0; j < 4; j++) {
            f16x2 qa; qa[0] = qh[2 * j];     qa[1] = qh[2 * j + 1];
            f16x2 ka; ka[0] = kh[ch][2 * j]; ka[1] = kh[ch][2 * j + 1];
            d = __builtin_amdgcn_fdot2(qa, ka, d, false);
        }
        d += __shfl_xor(d, 1);
        d += __shfl_xor(d, 2);
        d += __shfl_xor(d, 4);
        d += __shfl_xor(d, 8);
        sc[ch] = (mv[ch] == 1) ? d * 5.0f : -1e6f;
    }

    // Softmax over 32 (8 regs x 4 r-groups). All-masked s -> uniform 1/32,
    // matching the reference exactly.
    float mx = sc[0];
    #pragma unroll
    for (int ch = 1; ch < 8; ch++) mx = fmaxf(mx, sc[ch]);
    mx = fmaxf(mx, __shfl_xor(mx, 16));
    mx = fmaxf(mx, __shfl_xor(mx, 32));

    float p[8];
    float sum = 0.f;
    #pragma unroll
    for (int ch = 0; ch < 8; ch++) {
        p[ch] = __expf(sc[ch] - mx);   // masked: exp(-1e6 - mx) == +0.0f
        sum += p[ch];
    }
    sum += __shfl_xor(sum, 16);
    sum += __shfl_xor(sum, 32);
    const float inv = 1.0f / sum;
    #pragma unroll
    for (int ch = 0; ch < 8; ch++) p[ch] *= inv;

    // Agg gathers: lane (r,c) reads cols [c*8, c*8+8) of the 8 rows whose
    // probs it owns. Zero-prob rows redirected to src (hot, contributes 0).
    f16x8 vv[8];
    #pragma unroll
    for (int ch = 0; ch < 8; ch++) {
        const int row = (p[ch] != 0.f) ? nbv[ch] : src;
        vv[ch] = *(const f16x8*)(T + (size_t)row * 256 + 128 + c * 8);
    }

    float acc[8] = {0.f, 0.f, 0.f, 0.f, 0.f, 0.f, 0.f, 0.f};
    #pragma unroll
    for (int ch = 0; ch < 8; ch++) {
        #pragma unroll
        for (int j = 0; j < 8; j++)
            acc[j] += p[ch] * (float)vv[ch][j];
    }

    // Cross-group butterfly: sum the 4 r-group partials.
    #pragma unroll
    for (int j = 0; j < 8; j++) {
        acc[j] += __shfl_xor(acc[j], 16);
        acc[j] += __shfl_xor(acc[j], 32);
    }

    // lane (r,c) writes cols c*8 + r*2 + {0,1}: contiguous 512 B per wave.
    *((float2*)(out + (size_t)src * CC) + c * 4 + r) =
        make_float2(acc[r * 2], acc[r * 2 + 1]);
}

extern "C" void kernel_launch(void* const* d_in, const int* in_sizes, int n_in,
                              void* d_out, int out_size, void* d_ws, size_t ws_size,
                              hipStream_t stream)
{
    const float* wv   = (const float*)d_in[0];
    const int*   src  = (const int*)d_in[1];
    const int*   nei  = (const int*)d_in[2];
    const int*   msk  = (const int*)d_in[3];
    const float* W    = (const float*)d_in[4];
    const float* bias = (const float*)d_in[5];
    float* out = (float*)d_out;
    _Float16* T = (_Float16*)d_ws;   // 100000 * 512 B = 51.2 MB

    proj_kernel<<<NN / RPB, 256, 0, stream>>>(wv, W, bias, T, out);           // 625
    attn_kernel<<<(SS * 64) / 256, 256, 0, stream>>>(T, src, nei, msk, out);  // 12500
}